// Round 4
// baseline (465.390 us; speedup 1.0000x reference)
//
#include <hip/hip_runtime.h>
#include <cstddef>

#define NN 256          // nodes
#define VD 64           // V
#define ED 64           // E
#define SD 16           // S
#define HD 16           // H
#define EPS 65280       // edges per s = N*(N-1)
#define GRP_PER_S 510   // 128-edge groups per s
#define DE_GROUPS 8160  // SD * GRP_PER_S
#define DV_BLOCKS 4096  // SD * NN

typedef float f32x4 __attribute__((ext_vector_type(4)));

__device__ __forceinline__ float fast_tanh(float x) {
    // tanh(x) = 1 - 2/(exp(2x)+1); exp via v_exp_f32, rcp via v_rcp_f32.
    float e = __expf(2.0f * x);
    float r = __builtin_amdgcn_rcpf(e + 1.0f);
    return 1.0f - 2.0f * r;
}

// ---------------- Kernel P: per-node first-layer tables ----------------
__global__ __launch_bounds__(256) void precompute_ab(
    const float* __restrict__ v0, const float* __restrict__ we1,
    float* __restrict__ a_tab, float* __restrict__ b_tab) {
    int t = threadIdx.x;
    int i = t & 15;
    int nl = t >> 4;
    int node = blockIdx.x * 16 + nl;          // s*256+n, 0..4095
    const float* vrow = v0 + (size_t)node * VD;
    float a = 0.f, b = 0.f;
    #pragma unroll
    for (int k = 0; k < VD; ++k) {
        float x = vrow[k];
        a += x * we1[k * HD + i];
        b += x * we1[(VD + k) * HD + i];
    }
    a_tab[node * HD + i] = a;
    b_tab[node * HD + i] = b;
}

// ---------------- Fused kernel: de (2-tile pipelined) and dv interleaved ----------------
// Grid = 4096*3. bid%3==2 -> dv node (read-heavy, streams e0, NT loads).
// bid%3<2  -> de group of 128 edges, processed as two 64-edge tiles with a
// software pipeline: all gathers for BOTH tiles issue before the first
// barrier, so tile-1's gather latency hides under tile-0's compute+stores.
__global__ __launch_bounds__(256) void fused_dv_de(
    const float* __restrict__ e0,
    const float* __restrict__ wv1, const float* __restrict__ bv1,
    const float* __restrict__ wv2, const float* __restrict__ bv2,
    const float* __restrict__ a_tab, const float* __restrict__ b_tab,
    const float* __restrict__ we2, const float* __restrict__ be1,
    const float* __restrict__ be2,
    const int* __restrict__ recv_idx, const int* __restrict__ send_idx,
    float* __restrict__ dv_out, float* __restrict__ de_out) {
    __shared__ float smem[2560];              // de: 2 x 64*20 | dv: 1024+64+16
    int bid = blockIdx.x;
    int q = bid / 3;
    int r = bid - q * 3;                      // block-uniform branch selector
    int t = threadIdx.x;

    if (r == 2) {
        // ---------------- dv path: node = q ----------------
        float* red  = smem;                   // 16 groups x 64 e
        float* ev_s = smem + 1024;
        float* h_s  = smem + 1088;
        int node = q;                         // s*256+n
        const float* base = e0 + (size_t)node * 255 * ED;
        int c = t & 15;                       // float4 column (e/4)
        int g = t >> 4;                       // row group
        f32x4 acc = (f32x4){0.f, 0.f, 0.f, 0.f};
        for (int j = g; j < 255; j += 16) {
            const f32x4 v = __builtin_nontemporal_load(
                (const f32x4*)(base + (size_t)j * ED + c * 4));
            acc += v;
        }
        *(f32x4*)(red + g * 64 + c * 4) = acc;
        __syncthreads();
        if (t < 64) {
            float s = 0.f;
            #pragma unroll
            for (int gg = 0; gg < 16; ++gg) s += red[gg * 64 + t];
            ev_s[t] = s;
        }
        __syncthreads();
        if (t < 16) {
            float ah = bv1[t];
            #pragma unroll
            for (int e = 0; e < 64; ++e) ah += ev_s[e] * wv1[e * HD + t];
            h_s[t] = fast_tanh(ah);
        }
        __syncthreads();
        if (t < 64) {
            float o = bv2[t];
            #pragma unroll
            for (int i = 0; i < HD; ++i) o += h_s[i] * wv2[i * VD + t];
            dv_out[(size_t)node * VD + t] = o;
        }
    } else {
        // ---------------- de path: group dt = q*2+r (128 edges) ----------------
        int dt = q * 2 + r;
        if (dt >= DE_GROUPS) return;          // 32 tail blocks idle
        int s = dt / GRP_PER_S;
        int tile = dt - s * GRP_PER_S;        // 0..509
        float* h0 = smem;                     // tile0: 64 edges x stride 20
        float* h1 = smem + 1280;              // tile1

        int p = t & 63;
        int iq = t >> 6;                      // 0..3
        int eg0 = tile * 128 + p;             // edge index within s
        int eg1 = eg0 + 64;

        // ---- issue ALL gathers for both tiles up front ----
        int r0 = recv_idx[eg0], s0 = send_idx[eg0];
        int r1 = recv_idx[eg1], s1 = send_idx[eg1];
        const float4 b1  = *(const float4*)(be1 + iq * 4);
        const float4 av0 = *(const float4*)(a_tab + ((s << 8) + r0) * HD + iq * 4);
        const float4 bv0 = *(const float4*)(b_tab + ((s << 8) + s0) * HD + iq * 4);
        const float4 av1 = *(const float4*)(a_tab + ((s << 8) + r1) * HD + iq * 4);
        const float4 bv1 = *(const float4*)(b_tab + ((s << 8) + s1) * HD + iq * 4);

        float4 hv;
        hv.x = fast_tanh(av0.x + bv0.x + b1.x);
        hv.y = fast_tanh(av0.y + bv0.y + b1.y);
        hv.z = fast_tanh(av0.z + bv0.z + b1.z);
        hv.w = fast_tanh(av0.w + bv0.w + b1.w);
        *(float4*)(h0 + p * 20 + iq * 4) = hv;

        // preload we2 column v and bias (L1-resident across blocks)
        int v = t & 63;
        float w2[16];
        #pragma unroll
        for (int i = 0; i < HD; ++i) w2[i] = we2[i * ED + v];
        float bias = be2[v];
        __syncthreads();

        // tile1 activations (gathers long in flight) -> buf1, pre-barrier
        float4 g1;
        g1.x = fast_tanh(av1.x + bv1.x + b1.x);
        g1.y = fast_tanh(av1.y + bv1.y + b1.y);
        g1.z = fast_tanh(av1.z + bv1.z + b1.z);
        g1.w = fast_tanh(av1.w + bv1.w + b1.w);
        *(float4*)(h1 + p * 20 + iq * 4) = g1;

        // ---- phase 2 tile0: one wave per edge ----
        int w = t >> 6;                       // wave id, uniform in wave
        size_t outbase0 = ((size_t)s * EPS + (size_t)tile * 128) * ED;
        for (int pp = w * 16; pp < w * 16 + 16; ++pp) {
            const float* hp = h0 + pp * 20;
            float o = bias;
            #pragma unroll
            for (int i = 0; i < HD; i += 4) {
                float4 h4 = *(const float4*)(hp + i);   // broadcast, conflict-free
                o += h4.x * w2[i] + h4.y * w2[i + 1] + h4.z * w2[i + 2] + h4.w * w2[i + 3];
            }
            __builtin_nontemporal_store(o, de_out + outbase0 + (size_t)pp * ED + v);
        }
        __syncthreads();

        // ---- phase 2 tile1 ----
        size_t outbase1 = outbase0 + (size_t)64 * ED;
        for (int pp = w * 16; pp < w * 16 + 16; ++pp) {
            const float* hp = h1 + pp * 20;
            float o = bias;
            #pragma unroll
            for (int i = 0; i < HD; i += 4) {
                float4 h4 = *(const float4*)(hp + i);
                o += h4.x * w2[i] + h4.y * w2[i + 1] + h4.z * w2[i + 2] + h4.w * w2[i + 3];
            }
            __builtin_nontemporal_store(o, de_out + outbase1 + (size_t)pp * ED + v);
        }
    }
}

extern "C" void kernel_launch(void* const* d_in, const int* in_sizes, int n_in,
                              void* d_out, int out_size, void* d_ws, size_t ws_size,
                              hipStream_t stream) {
    // inputs: t, v0, e0, wv1, bv1, wv2, bv2, we1, be1, we2, be2, recv_idx, send_idx
    const float* v0   = (const float*)d_in[1];
    const float* e0   = (const float*)d_in[2];
    const float* wv1  = (const float*)d_in[3];
    const float* bv1  = (const float*)d_in[4];
    const float* wv2  = (const float*)d_in[5];
    const float* bv2  = (const float*)d_in[6];
    const float* we1  = (const float*)d_in[7];
    const float* be1  = (const float*)d_in[8];
    const float* we2  = (const float*)d_in[9];
    const float* be2  = (const float*)d_in[10];
    const int* recv_idx = (const int*)d_in[11];
    const int* send_idx = (const int*)d_in[12];

    float* dv_out = (float*)d_out;                       // S*N*V = 262144 floats
    float* de_out = dv_out + (size_t)SD * NN * VD;       // S*N*(N-1)*E
    float* a_tab  = (float*)d_ws;                        // 4096*16 floats
    float* b_tab  = a_tab + 4096 * HD;                   // 4096*16 floats

    precompute_ab<<<256, 256, 0, stream>>>(v0, we1, a_tab, b_tab);
    fused_dv_de<<<DV_BLOCKS * 3, 256, 0, stream>>>(
        e0, wv1, bv1, wv2, bv2, a_tab, b_tab, we2, be1, be2,
        recv_idx, send_idx, dv_out, de_out);
}

// Round 5
// 460.966 us; speedup vs baseline: 1.0096x; 1.0096x over previous
//
#include <hip/hip_runtime.h>
#include <cstddef>

#define NN 256          // nodes
#define VD 64           // V
#define ED 64           // E
#define SD 16           // S
#define HD 16           // H
#define EPS 65280       // edges per s = N*(N-1)
#define DV_BLOCKS 4096  // SD * NN
#define DE_ROWS 4096    // SD * NN (one block per (s, send-row i), 255 edges)

typedef float f32x4 __attribute__((ext_vector_type(4)));

__device__ __forceinline__ float fast_tanh(float x) {
    // tanh(x) = 1 - 2/(exp(2x)+1); exp via v_exp_f32, rcp via v_rcp_f32.
    float e = __expf(2.0f * x);
    float r = __builtin_amdgcn_rcpf(e + 1.0f);
    return 1.0f - 2.0f * r;
}

// ---------------- Kernel P: per-node first-layer tables ----------------
// a[s,n,i] = sum_k v0[s,n,k] * we1[k,i]        (recv half)
// b[s,n,i] = sum_k v0[s,n,k] * we1[64+k,i]     (send half)
__global__ __launch_bounds__(256) void precompute_ab(
    const float* __restrict__ v0, const float* __restrict__ we1,
    float* __restrict__ a_tab, float* __restrict__ b_tab) {
    int t = threadIdx.x;
    int i = t & 15;
    int nl = t >> 4;
    int node = blockIdx.x * 16 + nl;          // s*256+n, 0..4095
    const float* vrow = v0 + (size_t)node * VD;
    float a = 0.f, b = 0.f;
    #pragma unroll
    for (int k = 0; k < VD; ++k) {
        float x = vrow[k];
        a += x * we1[k * HD + i];
        b += x * we1[(VD + k) * HD + i];
    }
    a_tab[node * HD + i] = a;
    b_tab[node * HD + i] = b;
}

// ---------------- Fused kernel: de-row blocks and dv blocks interleaved 1:1 ----------------
// Grid = 4096*2. bid&1==1 -> dv node (streams 65 KB of e0 reads, NT).
// bid&1==0 -> de row (s,i): 255 edges, send==i uniform, recv==j consecutive.
// No index loads, no random gathers: b_tab[s,i] is one broadcast row,
// a_tab[s,j] is a coalesced consecutive stream (L2-resident).
__global__ __launch_bounds__(256) void fused_dv_de(
    const float* __restrict__ e0,
    const float* __restrict__ wv1, const float* __restrict__ bv1,
    const float* __restrict__ wv2, const float* __restrict__ bv2,
    const float* __restrict__ a_tab, const float* __restrict__ b_tab,
    const float* __restrict__ we2, const float* __restrict__ be1,
    const float* __restrict__ be2,
    float* __restrict__ dv_out, float* __restrict__ de_out) {
    __shared__ float smem[5100];              // de: 255 edges x stride 20 | dv: 1104
    int bid = blockIdx.x;
    int q = bid >> 1;
    int r = bid & 1;                          // block-uniform branch selector
    int t = threadIdx.x;

    if (r == 1) {
        // ---------------- dv path: node = q ----------------
        float* red  = smem;                   // 16 groups x 64 e
        float* ev_s = smem + 1024;
        float* h_s  = smem + 1088;
        int node = q;                         // s*256+n
        const float* base = e0 + (size_t)node * 255 * ED;
        int c = t & 15;                       // float4 column (e/4)
        int g = t >> 4;                       // row group
        f32x4 acc = (f32x4){0.f, 0.f, 0.f, 0.f};
        for (int j = g; j < 255; j += 16) {
            const f32x4 v = __builtin_nontemporal_load(
                (const f32x4*)(base + (size_t)j * ED + c * 4));
            acc += v;
        }
        *(f32x4*)(red + g * 64 + c * 4) = acc;
        __syncthreads();
        if (t < 64) {
            float s = 0.f;
            #pragma unroll
            for (int gg = 0; gg < 16; ++gg) s += red[gg * 64 + t];
            ev_s[t] = s;
        }
        __syncthreads();
        if (t < 16) {
            float ah = bv1[t];
            #pragma unroll
            for (int e = 0; e < 64; ++e) ah += ev_s[e] * wv1[e * HD + t];
            h_s[t] = fast_tanh(ah);
        }
        __syncthreads();
        if (t < 64) {
            float o = bv2[t];
            #pragma unroll
            for (int i = 0; i < HD; ++i) o += h_s[i] * wv2[i * VD + t];
            dv_out[(size_t)node * VD + t] = o;
        }
    } else {
        // ---------------- de path: row q -> (s, i), 255 edges ----------------
        int s = q >> 8;
        int i = q & 255;                      // send node (uniform for the row)
        float* h_s = smem;                    // 255 edges x stride 20

        int p = t & 63;
        int iq = t >> 6;                      // 0..3, wave-uniform

        // ---- phase 1: h[pp][iq*4..+3] for pp = p, p+64, p+128, p+192 ----
        const float4 b1 = *(const float4*)(be1 + iq * 4);
        const float4 bv = *(const float4*)(b_tab + ((s << 8) + i) * HD + iq * 4); // broadcast
        #pragma unroll
        for (int pp = p; pp < 255; pp += 64) {
            int j = pp + (pp >= i);           // recv node: consecutive, skip diagonal
            const float4 av = *(const float4*)(a_tab + ((s << 8) + j) * HD + iq * 4);
            float4 hv;
            hv.x = fast_tanh(av.x + bv.x + b1.x);
            hv.y = fast_tanh(av.y + bv.y + b1.y);
            hv.z = fast_tanh(av.z + bv.z + b1.z);
            hv.w = fast_tanh(av.w + bv.w + b1.w);
            *(float4*)(h_s + pp * 20 + iq * 4) = hv;
        }

        // preload we2 column v and bias (L1-resident across blocks)
        int v = t & 63;
        float w2[16];
        #pragma unroll
        for (int ii = 0; ii < HD; ++ii) w2[ii] = we2[ii * ED + v];
        float bias = be2[v];
        __syncthreads();

        // ---- phase 2: wave w handles edges [64w, min(64w+64,255)) ----
        int w = t >> 6;                       // wave id, uniform in wave
        size_t outbase = ((size_t)s * EPS + (size_t)i * 255) * ED;
        int ppend = (w == 3) ? 255 : (w * 64 + 64);
        for (int pp = w * 64; pp < ppend; ++pp) {
            const float* hp = h_s + pp * 20;
            float o = bias;
            #pragma unroll
            for (int ii = 0; ii < HD; ii += 4) {
                float4 h4 = *(const float4*)(hp + ii);  // broadcast, conflict-free
                o += h4.x * w2[ii] + h4.y * w2[ii + 1] + h4.z * w2[ii + 2] + h4.w * w2[ii + 3];
            }
            // 256B coalesced per wave; NT: bypass L2 (write-once stream)
            __builtin_nontemporal_store(o, de_out + outbase + (size_t)pp * ED + v);
        }
    }
}

extern "C" void kernel_launch(void* const* d_in, const int* in_sizes, int n_in,
                              void* d_out, int out_size, void* d_ws, size_t ws_size,
                              hipStream_t stream) {
    // inputs: t, v0, e0, wv1, bv1, wv2, bv2, we1, be1, we2, be2, recv_idx, send_idx
    const float* v0   = (const float*)d_in[1];
    const float* e0   = (const float*)d_in[2];
    const float* wv1  = (const float*)d_in[3];
    const float* bv1  = (const float*)d_in[4];
    const float* wv2  = (const float*)d_in[5];
    const float* bv2  = (const float*)d_in[6];
    const float* we1  = (const float*)d_in[7];
    const float* be1  = (const float*)d_in[8];
    const float* we2  = (const float*)d_in[9];
    const float* be2  = (const float*)d_in[10];

    float* dv_out = (float*)d_out;                       // S*N*V = 262144 floats
    float* de_out = dv_out + (size_t)SD * NN * VD;       // S*N*(N-1)*E
    float* a_tab  = (float*)d_ws;                        // 4096*16 floats
    float* b_tab  = a_tab + 4096 * HD;                   // 4096*16 floats

    precompute_ab<<<256, 256, 0, stream>>>(v0, we1, a_tab, b_tab);
    fused_dv_de<<<DV_BLOCKS * 2, 256, 0, stream>>>(
        e0, wv1, bv1, wv2, bv2, a_tab, b_tab, we2, be1, be2,
        dv_out, de_out);
}

// Round 7
// 454.180 us; speedup vs baseline: 1.0247x; 1.0149x over previous
//
#include <hip/hip_runtime.h>
#include <cstddef>

#define NN 256          // nodes
#define VD 64           // V
#define ED 64           // E
#define SD 16           // S
#define HD 16           // H
#define EPS 65280       // edges per s = N*(N-1)
#define DE_TILES 16320  // SD * EPS/64
#define DV_BLOCKS 4096  // SD * NN

typedef float f32x4 __attribute__((ext_vector_type(4)));

__device__ __forceinline__ float fast_tanh(float x) {
    // tanh(x) = 1 - 2/(exp(2x)+1); exp via v_exp_f32, rcp via v_rcp_f32.
    float e = __expf(2.0f * x);
    float r = __builtin_amdgcn_rcpf(e + 1.0f);
    return 1.0f - 2.0f * r;
}

// ---------------- Kernel P: per-node first-layer tables ----------------
// a[s,n,i] = sum_k v0[s,n,k] * we1[k,i]        (recv half)
// b[s,n,i] = sum_k v0[s,n,k] * we1[64+k,i]     (send half)
__global__ __launch_bounds__(256) void precompute_ab(
    const float* __restrict__ v0, const float* __restrict__ we1,
    float* __restrict__ a_tab, float* __restrict__ b_tab) {
    int t = threadIdx.x;
    int i = t & 15;
    int nl = t >> 4;
    int node = blockIdx.x * 16 + nl;          // s*256+n, 0..4095
    const float* vrow = v0 + (size_t)node * VD;
    float a = 0.f, b = 0.f;
    #pragma unroll
    for (int k = 0; k < VD; ++k) {
        float x = vrow[k];
        a += x * we1[k * HD + i];
        b += x * we1[(VD + k) * HD + i];
    }
    a_tab[node * HD + i] = a;
    b_tab[node * HD + i] = b;
}

// ---------------- Fused kernel: dv blocks and de blocks interleaved ----------------
// Grid = 4096*5 blocks. bid%5==4 -> dv node (read-heavy, streams e0, NT loads).
// bid%5<4  -> de tile (write-heavy, streams de_out, NT stores). Interleave keeps
// both read and write traffic live on HBM simultaneously; NT keeps the two
// touch-once streams from thrashing L2 (tables/weights stay resident).
// Per 5-block group: ~64 KB writes + ~65 KB reads — balanced per CU.
__global__ __launch_bounds__(256) void fused_dv_de(
    const float* __restrict__ e0,
    const float* __restrict__ wv1, const float* __restrict__ bv1,
    const float* __restrict__ wv2, const float* __restrict__ bv2,
    const float* __restrict__ a_tab, const float* __restrict__ b_tab,
    const float* __restrict__ we2, const float* __restrict__ be1,
    const float* __restrict__ be2,
    const int* __restrict__ recv_idx, const int* __restrict__ send_idx,
    float* __restrict__ dv_out, float* __restrict__ de_out) {
    __shared__ float smem[1344];              // dv: 1024+64+16 | de: 64*20
    int bid = blockIdx.x;
    int q = bid / 5;
    int r = bid - q * 5;                      // block-uniform branch selector
    int t = threadIdx.x;

    if (r == 4) {
        // ---------------- dv path: node = q ----------------
        float* red  = smem;                   // 16 groups x 64 e
        float* ev_s = smem + 1024;
        float* h_s  = smem + 1088;
        int node = q;                         // s*256+n
        const float* base = e0 + (size_t)node * 255 * ED;
        int c = t & 15;                       // float4 column (e/4)
        int g = t >> 4;                       // row group
        f32x4 acc = (f32x4){0.f, 0.f, 0.f, 0.f};
        for (int j = g; j < 255; j += 16) {
            const f32x4 v = __builtin_nontemporal_load(
                (const f32x4*)(base + (size_t)j * ED + c * 4));
            acc += v;
        }
        *(f32x4*)(red + g * 64 + c * 4) = acc;
        __syncthreads();
        if (t < 64) {
            float s = 0.f;
            #pragma unroll
            for (int gg = 0; gg < 16; ++gg) s += red[gg * 64 + t];
            ev_s[t] = s;
        }
        __syncthreads();
        if (t < 16) {
            float ah = bv1[t];
            #pragma unroll
            for (int e = 0; e < 64; ++e) ah += ev_s[e] * wv1[e * HD + t];
            h_s[t] = fast_tanh(ah);
        }
        __syncthreads();
        if (t < 64) {
            float o = bv2[t];
            #pragma unroll
            for (int i = 0; i < HD; ++i) o += h_s[i] * wv2[i * VD + t];
            dv_out[(size_t)node * VD + t] = o;
        }
    } else {
        // ---------------- de path: tile dt = q*4+r ----------------
        int dt = q * 4 + r;
        if (dt >= DE_TILES) return;           // 64 tail blocks idle
        int s = dt / 1020;                    // 1020 tiles per s
        int tile = dt - s * 1020;
        float* h_s = smem;                    // 64 edges x stride 20

        int p = t & 63;
        int iq = t >> 6;                      // 0..3
        int eg = tile * 64 + p;               // edge index within s

        // ---- phase 1: activations ----
        int rr = recv_idx[eg];
        int sd = send_idx[eg];
        const float4 av = *(const float4*)(a_tab + ((s << 8) + rr) * HD + iq * 4);
        const float4 bv = *(const float4*)(b_tab + ((s << 8) + sd) * HD + iq * 4);
        const float4 b1 = *(const float4*)(be1 + iq * 4);
        float4 hv;
        hv.x = fast_tanh(av.x + bv.x + b1.x);
        hv.y = fast_tanh(av.y + bv.y + b1.y);
        hv.z = fast_tanh(av.z + bv.z + b1.z);
        hv.w = fast_tanh(av.w + bv.w + b1.w);
        *(float4*)(h_s + p * 20 + iq * 4) = hv;

        // preload we2 column v and bias (L1-resident across blocks)
        int v = t & 63;
        float w2[16];
        #pragma unroll
        for (int i = 0; i < HD; ++i) w2[i] = we2[i * ED + v];
        float bias = be2[v];
        __syncthreads();

        // ---- phase 2: one wave per edge ----
        int w = t >> 6;                       // wave id, uniform in wave
        size_t outbase = ((size_t)s * EPS + (size_t)tile * 64) * ED;
        for (int pp = w * 16; pp < w * 16 + 16; ++pp) {
            const float* hp = h_s + pp * 20;
            float o = bias;
            #pragma unroll
            for (int i = 0; i < HD; i += 4) {
                float4 h4 = *(const float4*)(hp + i);   // broadcast, conflict-free
                o += h4.x * w2[i] + h4.y * w2[i + 1] + h4.z * w2[i + 2] + h4.w * w2[i + 3];
            }
            // 256B coalesced per wave; NT: bypass L2 (write-once stream)
            __builtin_nontemporal_store(o, de_out + outbase + (size_t)pp * ED + v);
        }
    }
}

extern "C" void kernel_launch(void* const* d_in, const int* in_sizes, int n_in,
                              void* d_out, int out_size, void* d_ws, size_t ws_size,
                              hipStream_t stream) {
    // inputs: t, v0, e0, wv1, bv1, wv2, bv2, we1, be1, we2, be2, recv_idx, send_idx
    const float* v0   = (const float*)d_in[1];
    const float* e0   = (const float*)d_in[2];
    const float* wv1  = (const float*)d_in[3];
    const float* bv1  = (const float*)d_in[4];
    const float* wv2  = (const float*)d_in[5];
    const float* bv2  = (const float*)d_in[6];
    const float* we1  = (const float*)d_in[7];
    const float* be1  = (const float*)d_in[8];
    const float* we2  = (const float*)d_in[9];
    const float* be2  = (const float*)d_in[10];
    const int* recv_idx = (const int*)d_in[11];
    const int* send_idx = (const int*)d_in[12];

    float* dv_out = (float*)d_out;                       // S*N*V = 262144 floats
    float* de_out = dv_out + (size_t)SD * NN * VD;       // S*N*(N-1)*E
    float* a_tab  = (float*)d_ws;                        // 4096*16 floats
    float* b_tab  = a_tab + 4096 * HD;                   // 4096*16 floats

    precompute_ab<<<256, 256, 0, stream>>>(v0, we1, a_tab, b_tab);
    fused_dv_de<<<DV_BLOCKS * 5, 256, 0, stream>>>(
        e0, wv1, bv1, wv2, bv2, a_tab, b_tab, we2, be1, be2,
        recv_idx, send_idx, dv_out, de_out);
}